// Round 15
// baseline (366.294 us; speedup 1.0000x reference)
//
#include <hip/hip_runtime.h>

#define BB 128
#define TT 256
#define CCH 384
#define NHH 6
#define HSZ 64
#define BTT (BB*TT)
#define QKVLD 1152

typedef unsigned short u16;
typedef unsigned int   u32;
typedef __attribute__((ext_vector_type(8))) short  short8;   // 8 x bf16 (4 VGPR)
typedef __attribute__((ext_vector_type(4))) float  floatx4;  // MFMA C/D

__device__ __forceinline__ u16 f2bf(float f) {
  union { float f; u32 i; } v; v.f = f; u32 x = v.i;
  return (u16)((x + 0x7fffu + ((x >> 16) & 1u)) >> 16);
}
__device__ __forceinline__ float bf2f(u16 w) {
  union { u32 i; float f; } v; v.i = ((u32)w) << 16; return v.f;
}
__device__ __forceinline__ float rndbf(float f) { return bf2f(f2bf(f)); }

// async global->LDS, 16B per lane; LDS dest is wave-uniform base + lane*16
__device__ __forceinline__ void gll16(const u16* g, u16* l) {
  __builtin_amdgcn_global_load_lds((const __attribute__((address_space(1))) void*)g,
                                   (__attribute__((address_space(3))) void*)l, 16, 0, 0);
}

// ------------- prep_all: repack (LN-gamma pre-scaled) + x cast + LN1 stats + c1/c2 ----
// LN fold identity: LN(x)@W = rinv*(x@(g*W)) - rinv*mu*c1 + c2,
//   c1[n] = sum_k rounded(g[k]*W[n,k])  (rounded -> exact cancellation vs MFMA),
//   c2[n] = sum_k beta[k]*W[n,k].
// Blocks [0,6912): repack (wqkv scaled by ln1g, w1 scaled by ln2g; wp/w2 raw).
// Blocks [6912,15104): cast x->xb (bf16) + LN1 row stats -> st1[row] = {mu, rinv}.
// Blocks [15104,15776): c1/c2 for qkv (1152 cols) and w1 (1536 cols), 1 wave/col.
__global__ __launch_bounds__(256) void prep_all(const float* __restrict__ wq,
                                                const float* __restrict__ wk,
                                                const float* __restrict__ wv,
                                                const float* __restrict__ wproj,
                                                const float* __restrict__ w1,
                                                const float* __restrict__ w2,
                                                u16* __restrict__ wqkv_t, u16* __restrict__ wp_t,
                                                u16* __restrict__ w1_t, u16* __restrict__ w2_t,
                                                const float* __restrict__ x,
                                                const float* __restrict__ ln1g,
                                                const float* __restrict__ ln1b,
                                                const float* __restrict__ ln2g,
                                                const float* __restrict__ ln2b,
                                                u16* __restrict__ xb,
                                                float* __restrict__ st1,
                                                float* __restrict__ c1q, float* __restrict__ c2q,
                                                float* __restrict__ c1m, float* __restrict__ c2m) {
  const int bidx = blockIdx.x;
  if (bidx < 6912) {
    int idx = bidx * 256 + threadIdx.x;
    const int S1 = 442368;            // 72 nb * 12 kt * 512
    const int S2 = S1 + 147456;       // 24 * 12 * 512
    const int S3 = S2 + 589824;       // 96 * 12 * 512
    const int S4 = S3 + 589824;       // 24 * 48 * 512
    if (idx < S1) {
      int i = idx, e = i & 7, l = (i >> 3) & 63, r = i >> 9;
      int kt = r % 12, nb = r / 12;
      int n = nb * 16 + (l & 15), k = kt * 32 + (l >> 4) * 8 + e;
      int sel = n / 384, nn = n % 384;
      size_t src = ((size_t)(nn >> 6) * 384 + k) * 64 + (nn & 63);
      float v = (sel == 0) ? wq[src] : (sel == 1) ? wk[src] : wv[src];
      wqkv_t[i] = f2bf(ln1g[k] * v);
    } else if (idx < S2) {
      int i = idx - S1, e = i & 7, l = (i >> 3) & 63, r = i >> 9;
      int kt = r % 12, nb = r / 12;
      int n = nb * 16 + (l & 15), k = kt * 32 + (l >> 4) * 8 + e;
      wp_t[i] = f2bf(wproj[(size_t)k * 384 + n]);
    } else if (idx < S3) {
      int i = idx - S2, e = i & 7, l = (i >> 3) & 63, r = i >> 9;
      int kt = r % 12, nb = r / 12;
      int n = nb * 16 + (l & 15), k = kt * 32 + (l >> 4) * 8 + e;
      w1_t[i] = f2bf(ln2g[k] * w1[(size_t)k * 1536 + n]);
    } else if (idx < S4) {
      int i = idx - S3, e = i & 7, l = (i >> 3) & 63, r = i >> 9;
      int kt = r % 48, nb = r / 48;
      int n = nb * 16 + (l & 15), k = kt * 32 + (l >> 4) * 8 + e;
      w2_t[i] = f2bf(w2[(size_t)k * 384 + n]);
    }
  } else if (bidx < 15104) {
    int row = (bidx - 6912) * 4 + (threadIdx.x >> 6);
    int lane = threadIdx.x & 63;
    const float* xr = x + (size_t)row * CCH;
    float vals[6];
    float sum = 0.f;
#pragma unroll
    for (int i = 0; i < 6; ++i) { vals[i] = xr[lane + (i << 6)]; sum += vals[i]; }
#pragma unroll
    for (int off = 32; off; off >>= 1) sum += __shfl_xor(sum, off);
    float mean = sum * (1.f / 384.f);
    float vs = 0.f;
#pragma unroll
    for (int i = 0; i < 6; ++i) { float d = vals[i] - mean; vs += d * d; }
#pragma unroll
    for (int off = 32; off; off >>= 1) vs += __shfl_xor(vs, off);
    float rinv = rsqrtf(vs * (1.f / 384.f) + 1e-5f);
    u16* orow = xb + (size_t)row * CCH;
#pragma unroll
    for (int i = 0; i < 6; ++i) orow[lane + (i << 6)] = f2bf(vals[i]);
    if (lane == 0) { st1[2 * row] = mean; st1[2 * row + 1] = rinv; }
  } else {
    int col = (bidx - 15104) * 4 + (threadIdx.x >> 6);
    int lane = threadIdx.x & 63;
    float s1 = 0.f, s2 = 0.f;
    if (col < 1152) {
      int sel = col / 384, nn = col % 384;
      const float* wsel = (sel == 0) ? wq : (sel == 1) ? wk : wv;
#pragma unroll
      for (int i = 0; i < 6; ++i) {
        int k = lane + (i << 6);
        float v = wsel[((size_t)(nn >> 6) * 384 + k) * 64 + (nn & 63)];
        s1 += rndbf(ln1g[k] * v);
        s2 += ln1b[k] * v;
      }
#pragma unroll
      for (int off = 32; off; off >>= 1) { s1 += __shfl_xor(s1, off); s2 += __shfl_xor(s2, off); }
      if (lane == 0) { c1q[col] = s1; c2q[col] = s2; }
    } else {
      int n = col - 1152;
#pragma unroll
      for (int i = 0; i < 6; ++i) {
        int k = lane + (i << 6);
        float v = w1[(size_t)k * 1536 + n];
        s1 += rndbf(ln2g[k] * v);
        s2 += ln2b[k] * v;
      }
#pragma unroll
      for (int off = 32; off; off >>= 1) { s1 += __shfl_xor(s1, off); s2 += __shfl_xor(s2, off); }
      if (lane == 0) { c1m[n] = s1; c2m[n] = s2; }
    }
  }
}

// ---- gemm_kres3: K=384-resident GEMM, 64x192 block, 3 waves 1Mx3N ----
// R10/R13-proven: per-kt [64][32] chunk-XOR A-tiles (0 conflicts), disjoint
// per-wave B reg-prefetch depth-2 (R13: best depth; R14 depth-3 was worse),
// one stage-barrier then barrier-free unrolled k-loop.
// LNFOLD=1: apply LN1 fold (st = {mu,rinv} per row) in epilogue.
// LNFOLD=2: apply LN2 fold from 2-part partial sums (stin[row*4] = p0,q0,p1,q1).
// STATSOUT: emit this block's partial row {sum,sumsq} over its 192 cols.
template <int BIAS, int RES, int RELU, int OUTBF, int RESBF, int LNFOLD, int STATSOUT>
__global__ __launch_bounds__(192, 2) void gemm_kres3(const u16* __restrict__ A,
                                                     const u16* __restrict__ Bp,
                                                     const float* __restrict__ bias,
                                                     const void* __restrict__ resv,
                                                     void* __restrict__ outv,
                                                     int M, int N,
                                                     const float* __restrict__ stin,
                                                     float* __restrict__ stout,
                                                     const float* __restrict__ c1,
                                                     const float* __restrict__ c2) {
  __shared__ __align__(16) u16 Ah[12 * 2048];   // 12 kt-tiles of [64][32], 48 KB
  __shared__ float wpart[64][4][2];             // STATSOUT combine (2KB)
  const int tid = threadIdx.x;
  const int lane = tid & 63;
  const int w = tid >> 6;                 // wave 0..2; owns cols [64w, 64w+64)

  // XCD swizzle (bijective since nwg % 8 == 0)
  const int gx = gridDim.x;
  const int nwg = gx * gridDim.y;
  const int bid = blockIdx.y * gx + blockIdx.x;
  const int lin = (bid & 7) * (nwg >> 3) + (bid >> 3);
  const int m0 = (lin / gx) * 64, n0 = (lin % gx) * 192;

  const int lm = lane & 15, qd = lane >> 4;

  // ---- stage all 12 A kt-tiles: 16 gll16/wave, chunk-XOR per tile ----
#pragma unroll
  for (int g = 0; g < 16; ++g) {
    int call = w * 16 + g;                // 0..47
    int kt = call >> 2, c = call & 3;     // tile, 16-row group
    int row = 16 * c + (lane >> 2);
    int ch = (lane & 3) ^ ((row >> 1) & 3);
    const u16* src = A + (size_t)(m0 + row) * 384 + kt * 32 + ch * 8;
    gll16(src, &Ah[kt * 2048 + c * 512]);
  }

  // B fragment bases: wave w's 4 n-blocks (nb = n0/16 + 4w + j), KT=12
  const u16* bsrc[4];
#pragma unroll
  for (int j = 0; j < 4; ++j)
    bsrc[j] = Bp + ((size_t)((n0 >> 4) + 4 * w + j) * 12) * 512 + lane * 8;

  floatx4 acc[4][4];
  floatx4 zero4 = {0.f, 0.f, 0.f, 0.f};
#pragma unroll
  for (int i = 0; i < 4; ++i)
#pragma unroll
    for (int j = 0; j < 4; ++j) acc[i][j] = zero4;

  // depth-2 B prefetch: 3-buffer rotation (all indices static after unroll)
  short8 bf[3][4];
#pragma unroll
  for (int j = 0; j < 4; ++j) bf[0][j] = *(const short8*)(bsrc[j]);          // kt=0
#pragma unroll
  for (int j = 0; j < 4; ++j) bf[1][j] = *(const short8*)(bsrc[j] + 512);    // kt=1

  asm volatile("s_waitcnt vmcnt(0)" ::: "memory");   // A-tiles + bf[0..1] resident
  __syncthreads();                                   // the ONLY pre-epilogue barrier

  // ---- barrier-free k-loop, fully unrolled, depth-2 B pipeline ----
#pragma unroll
  for (int kt = 0; kt < 12; ++kt) {
    if (kt + 2 < 12) {
      const int pb = (kt + 2) % 3;
#pragma unroll
      for (int j = 0; j < 4; ++j)
        bf[pb][j] = *(const short8*)(bsrc[j] + (kt + 2) * 512);
    }
    const int cb = kt % 3;
    short8 af[4];
#pragma unroll
    for (int i = 0; i < 4; ++i) {
      int rm = 16 * i + lm;
      af[i] = *(const short8*)&Ah[kt * 2048 + rm * 32 + (qd ^ ((rm >> 1) & 3)) * 8];
    }
#pragma unroll
    for (int i = 0; i < 4; ++i)
#pragma unroll
      for (int j = 0; j < 4; ++j)
        acc[i][j] = __builtin_amdgcn_mfma_f32_16x16x32_bf16(af[i], bf[cb][j], acc[i][j], 0, 0, 0);
  }

  // epilogue: C/D layout col=lm, row=qd*4+r
  float rs[4][4], rq[4][4];   // STATSOUT row partials
#pragma unroll
  for (int i = 0; i < 4; ++i) {
    int row0 = m0 + 16 * i + qd * 4;
    float mu_[4], ri_[4];
    if (LNFOLD == 1) {
#pragma unroll
      for (int r = 0; r < 4; ++r) {
        mu_[r] = stin[2 * (row0 + r)];
        ri_[r] = stin[2 * (row0 + r) + 1];
      }
    } else if (LNFOLD == 2) {
#pragma unroll
      for (int r = 0; r < 4; ++r) {
        float p0 = stin[(row0 + r) * 4 + 0], q0 = stin[(row0 + r) * 4 + 1];
        float p1 = stin[(row0 + r) * 4 + 2], q1 = stin[(row0 + r) * 4 + 3];
        float mu = (p0 + p1) * (1.f / 384.f);
        float var = (q0 + q1) * (1.f / 384.f) - mu * mu;
        mu_[r] = mu;
        ri_[r] = rsqrtf(var + 1e-5f);
      }
    }
    if (STATSOUT) {
#pragma unroll
      for (int r = 0; r < 4; ++r) { rs[i][r] = 0.f; rq[i][r] = 0.f; }
    }
#pragma unroll
    for (int j = 0; j < 4; ++j) {
      int col = n0 + 64 * w + 16 * j + lm;
      float bb = 0.f;
      if (BIAS) bb = bias[col];
      float c1v = 0.f, c2v = 0.f;
      if (LNFOLD) { c1v = c1[col]; c2v = c2[col]; }
#pragma unroll
      for (int r = 0; r < 4; ++r) {
        size_t idx = (size_t)(row0 + r) * N + col;
        float val;
        if (LNFOLD) val = ri_[r] * (acc[i][j][r] - mu_[r] * c1v) + c2v + bb;
        else        val = acc[i][j][r] + bb;
        if (RES) val += RESBF ? bf2f(((const u16*)resv)[idx]) : ((const float*)resv)[idx];
        if (RELU) val = fmaxf(val, 0.f);
        if (STATSOUT) { rs[i][r] += val; rq[i][r] += val * val; }
        if (OUTBF) ((u16*)outv)[idx] = f2bf(val);
        else       ((float*)outv)[idx] = val;
      }
    }
  }

  if (STATSOUT) {
    const int cbk = n0 / 192 & 1;       // which half of N=384
#pragma unroll
    for (int i = 0; i < 4; ++i) {
#pragma unroll
      for (int r = 0; r < 4; ++r) {
        float s = rs[i][r], q = rq[i][r];
#pragma unroll
        for (int off = 1; off < 16; off <<= 1) {
          s += __shfl_xor(s, off);
          q += __shfl_xor(q, off);
        }
        if (lm == 0) {
          int rl = 16 * i + qd * 4 + r;
          wpart[rl][w][0] = s;
          wpart[rl][w][1] = q;
        }
      }
    }
    __syncthreads();
    if (tid < 64) {
      float S = wpart[tid][0][0] + wpart[tid][1][0] + wpart[tid][2][0];
      float Q = wpart[tid][0][1] + wpart[tid][1][1] + wpart[tid][2][1];
      stout[(size_t)(m0 + tid) * 4 + cbk * 2 + 0] = S;
      stout[(size_t)(m0 + tid) * 4 + cbk * 2 + 1] = Q;
    }
  }
}

// ---- MFMA GEMM v3 (R8-proven, for MLP2 K=1536): 128x128 tile, BK=32,
// A in LDS dbuf, B register-direct from frag-linear Bp, depth-1 prefetch. ----
template <int BIAS, int RES, int RELU, int OUTBF, int RESBF>
__global__ __launch_bounds__(256, 3) void gemm_mfma(const u16* __restrict__ A,
                                                    const u16* __restrict__ Bp,
                                                    const float* __restrict__ bias,
                                                    const void* __restrict__ resv,
                                                    void* __restrict__ outv,
                                                    int M, int N, int K) {
  __shared__ __align__(16) u16 As[2][128 * 32];
  const int tid = threadIdx.x;
  const int lane = tid & 63;
  const int w = tid >> 6;                 // wave 0..3
  const int wr = w >> 1, wc = w & 1;      // 2x2 wave grid, wave tile 64x64

  const int gx = gridDim.x;
  const int nwg = gx * gridDim.y;
  const int bid = blockIdx.y * gx + blockIdx.x;
  const int lin = (bid & 7) * (nwg >> 3) + (bid >> 3);
  const int m0 = (lin / gx) * 128, n0 = (lin % gx) * 128;

  const int lm = lane & 15, qd = lane >> 4;
  const int KT = K >> 5;

  floatx4 acc[4][4];
  floatx4 zero4 = {0.f, 0.f, 0.f, 0.f};
#pragma unroll
  for (int i = 0; i < 4; ++i)
#pragma unroll
    for (int j = 0; j < 4; ++j) acc[i][j] = zero4;

  const u16* srcA[2];
#pragma unroll
  for (int c = 0; c < 2; ++c) {
    int row = 32 * w + 16 * c + (lane >> 2);
    int ch = (lane & 3) ^ ((row >> 1) & 3);
    srcA[c] = A + (size_t)(m0 + row) * K + ch * 8;
  }
  const int dA = (32 * w) * 32;

  const u16* bsrc[4];
#pragma unroll
  for (int j = 0; j < 4; ++j)
    bsrc[j] = Bp + ((size_t)((n0 >> 4) + 4 * wc + j) * KT) * 512 + lane * 8;

#pragma unroll
  for (int c = 0; c < 2; ++c) gll16(srcA[c], &As[0][dA + 512 * c]);
  short8 bcur[4], bnxt[4];
#pragma unroll
  for (int j = 0; j < 4; ++j) bcur[j] = *(const short8*)(bsrc[j]);

  for (int k0 = 0; k0 < K; k0 += 64) {
    __syncthreads();
    {
      int kn = k0 + 32;
      int kto = (kn >> 5) << 9;
#pragma unroll
      for (int j = 0; j < 4; ++j) bnxt[j] = *(const short8*)(bsrc[j] + kto);
#pragma unroll
      for (int c = 0; c < 2; ++c) gll16(srcA[c] + kn, &As[1][dA + 512 * c]);
      short8 af[4];
#pragma unroll
      for (int i = 0; i < 4; ++i) {
        int rm = 64 * wr + 16 * i + lm;
        af[i] = *(const short8*)&As[0][rm * 32 + (qd ^ ((rm >> 1) & 3)) * 8];
      }
#pragma unroll
      for (int i = 0; i < 4; ++i)
#pragma unroll
        for (int j = 0; j < 4; ++j)
          acc[i][j] = __builtin_amdgcn_mfma_f32_16x16x32_bf16(af[i], bcur[j], acc[i][j], 0, 0, 0);
    }
    __syncthreads();
    {
      int kn = k0 + 64;
      if (kn < K) {
        int kto = (kn >> 5) << 9;
#pragma unroll
        for (int j = 0; j < 4; ++j) bcur[j] = *(const short8*)(bsrc[j] + kto);
#pragma unroll
        for (int c = 0; c < 2; ++c) gll16(srcA[c] + kn, &As[0][dA + 512 * c]);
      }
      short8 af[4];
#pragma unroll
      for (int i = 0; i < 4; ++i) {
        int rm = 64 * wr + 16 * i + lm;
        af[i] = *(const short8*)&As[1][rm * 32 + (qd ^ ((rm >> 1) & 3)) * 8];
      }
#pragma unroll
      for (int i = 0; i < 4; ++i)
#pragma unroll
        for (int j = 0; j < 4; ++j)
          acc[i][j] = __builtin_amdgcn_mfma_f32_16x16x32_bf16(af[i], bnxt[j], acc[i][j], 0, 0, 0);
    }
  }

#pragma unroll
  for (int i = 0; i < 4; ++i) {
    int row0 = m0 + 64 * wr + 16 * i + qd * 4;
#pragma unroll
    for (int j = 0; j < 4; ++j) {
      int col = n0 + 64 * wc + 16 * j + lm;
      float bb = 0.f;
      if (BIAS) bb = bias[col];
#pragma unroll
      for (int r = 0; r < 4; ++r) {
        size_t idx = (size_t)(row0 + r) * N + col;
        float val = acc[i][j][r] + bb;
        if (RES) val += RESBF ? bf2f(((const u16*)resv)[idx]) : ((const float*)resv)[idx];
        if (RELU) val = fmaxf(val, 0.f);
        if (OUTBF) ((u16*)outv)[idx] = f2bf(val);
        else       ((float*)outv)[idx] = val;
      }
    }
  }
}

// ---------------- MFMA attention, column(query-axis) softmax ----------------
#define ASCALE 0.051031036307982884f

__global__ __launch_bounds__(1024) void attn_mfma(const u16* __restrict__ qkv,
                                                  u16* __restrict__ out) {
  __shared__ __align__(16) char lds_raw[36864 + 20480 + 2048];
  u16*   Ks       = (u16*)lds_raw;
  u16*   VT       = (u16*)lds_raw;
  float* partials = (float*)(lds_raw + 36864);
  u16*   stage    = (u16*)(lds_raw + 36864);
  float* gmax     = (float*)(lds_raw + 57344);
  float* linv     = (float*)(lds_raw + 58368);

  const int tid = threadIdx.x;
  const int lane = tid & 63;
  const int w = tid >> 6;           // wave 0..15 owns S rows [16w,16w+16)
  const int lm = lane & 15, qd = lane >> 4;
  const int b = blockIdx.x / NHH, h = blockIdx.x % NHH;
  const size_t rowbase = (size_t)b * TT;
  const u16* qp = qkv + rowbase * QKVLD + h * HSZ;
  const u16* kp = qp + 384;
  const u16* vp = qp + 768;

  {
    int s = tid >> 2, c4 = tid & 3;
    const u16* src = kp + (size_t)s * QKVLD;
    *(uint4*)&Ks[s * 72 + c4 * 8]       = *(const uint4*)(src + c4 * 8);
    *(uint4*)&Ks[s * 72 + (c4 + 4) * 8] = *(const uint4*)(src + (c4 + 4) * 8);
  }
  short8 qf0, qf1;
  {
    const u16* qrow = qp + (size_t)(16 * w + lm) * QKVLD + qd * 8;
    qf0 = *(const short8*)(qrow);
    qf1 = *(const short8*)(qrow + 32);
  }
  __syncthreads();

  floatx4 acc[16];
  floatx4 zero4 = {0.f, 0.f, 0.f, 0.f};
#pragma unroll
  for (int tc = 0; tc < 16; ++tc) acc[tc] = zero4;

#pragma unroll
  for (int tc = 0; tc < 16; ++tc) {
    if (tc <= w) {
      int sr = 16 * tc + lm;
      short8 kf0 = *(const short8*)&Ks[sr * 72 + qd * 8];
      short8 kf1 = *(const short8*)&Ks[sr * 72 + 32 + qd * 8];
      acc[tc] = __builtin_amdgcn_mfma_f32_16x16x32_bf16(qf0, kf0, acc[tc], 0, 0, 0);
      acc[tc] = __builtin_amdgcn_mfma_f32_16x16x32_bf16(qf1, kf1, acc[tc], 0, 0, 0);
    }
  }

  const int rb = 16 * w + qd * 4;
  float pmax[16];
#pragma unroll
  for (int tc = 0; tc < 16; ++tc) {
    float m = -1e30f;
    if (tc <= w) {
      int sc = 16 * tc + lm;
#pragma unroll
      for (int r = 0; r < 4; ++r) {
        float vv = acc[tc][r] * ASCALE;
        vv = (rb + r >= sc) ? vv : -1e30f;
        acc[tc][r] = vv;
        m = fmaxf(m, vv);
      }
    }
    m = fmaxf(m, __shfl_xor(m, 16));
    m = fmaxf(m, __shfl_xor(m, 32));
    pmax[tc] = m;
  }
  if (lane < 16) {
#pragma unroll
    for (int tc = 0; tc < 16; ++tc) partials[w * 256 + tc * 16 + lane] = pmax[tc];
  }
  __syncthreads();
  if (tid < 256) {
    float m = partials[tid];
#pragma unroll
    for (int i = 1; i < 16; ++i) m = fmaxf(m, partials[i * 256 + tid]);
    gmax[tid] = m;
  }
  __syncthreads();

  float psum[16];
#pragma unroll
  for (int tc = 0; tc < 16; ++tc) {
    float s = 0.f;
    if (tc <= w) {
      float gm = gmax[tc * 16 + lm];
#pragma unroll
      for (int r = 0; r < 4; ++r) {
        float e = (acc[tc][r] > -1e29f) ? __expf(acc[tc][r] - gm) : 0.f;
        acc[tc][r] = e;
        s += e;
      }
    }
    s += __shfl_xor(s, 16);
    s += __shfl_xor(s, 32);
    psum[tc] = s;
  }
  if (lane < 16) {
#pragma unroll
    for (int tc = 0; tc < 16; ++tc) partials[w * 256 + tc * 16 + lane] = psum[tc];
  }
  __syncthreads();
  if (tid < 256) {
    float s = partials[tid];
#pragma unroll
    for (int i = 1; i < 16; ++i) s += partials[i * 256 + tid];
    linv[tid] = 1.f / s;
  }
  __syncthreads();

  {
    int s = tid >> 2, dg = (tid & 3) * 16;
    const u16* vrow = vp + (size_t)s * QKVLD + dg;
    u16 tmp[16];
    *(uint4*)&tmp[0] = *(const uint4*)(vrow);
    *(uint4*)&tmp[8] = *(const uint4*)(vrow + 8);
#pragma unroll
    for (int j = 0; j < 16; ++j) VT[(dg + j) * 264 + s] = tmp[j];
  }
  __syncthreads();

  u16* mst = stage + w * 640;
  floatx4 oacc[4];
#pragma unroll
  for (int nt = 0; nt < 4; ++nt) oacc[nt] = zero4;

#pragma unroll
  for (int c = 0; c < 8; ++c) {
    if (2 * c <= w) {
#pragma unroll
      for (int tt = 0; tt < 2; ++tt) {
        int tc = 2 * c + tt;
        float li = (tc <= w) ? linv[tc * 16 + lm] : 0.f;
#pragma unroll
        for (int r = 0; r < 4; ++r) {
          float pv = (tc <= w) ? acc[tc][r] * li : 0.f;
          mst[(qd * 4 + r) * 40 + tt * 16 + lm] = f2bf(pv);
        }
      }
      asm volatile("s_waitcnt lgkmcnt(0)" ::: "memory");
      short8 pf = *(const short8*)&mst[lm * 40 + qd * 8];
#pragma unroll
      for (int nt = 0; nt < 4; ++nt) {
        short8 vf = *(const short8*)&VT[(nt * 16 + lm) * 264 + c * 32 + qd * 8];
        oacc[nt] = __builtin_amdgcn_mfma_f32_16x16x32_bf16(pf, vf, oacc[nt], 0, 0, 0);
      }
      asm volatile("" ::: "memory");
    }
  }

  u16* ob = out + rowbase * CCH + h * HSZ;
#pragma unroll
  for (int nt = 0; nt < 4; ++nt) {
#pragma unroll
    for (int r = 0; r < 4; ++r) {
      int t = 16 * w + qd * 4 + r;
      ob[(size_t)t * CCH + nt * 16 + lm] = f2bf(oacc[nt][r]);
    }
  }
}

// ---------------- launch ----------------
extern "C" void kernel_launch(void* const* d_in, const int* in_sizes, int n_in,
                              void* d_out, int out_size, void* d_ws, size_t ws_size,
                              hipStream_t stream) {
  const float* x     = (const float*)d_in[0];
  const float* wq    = (const float*)d_in[1];
  const float* wk    = (const float*)d_in[2];
  const float* wv    = (const float*)d_in[3];
  const float* wproj = (const float*)d_in[4];
  const float* bproj = (const float*)d_in[5];
  const float* w1    = (const float*)d_in[6];
  const float* b1    = (const float*)d_in[7];
  const float* w2    = (const float*)d_in[8];
  const float* b2    = (const float*)d_in[9];
  const float* ln1g  = (const float*)d_in[10];
  const float* ln1b  = (const float*)d_in[11];
  const float* ln2g  = (const float*)d_in[12];
  const float* ln2b  = (const float*)d_in[13];
  float* out = (float*)d_out;
  (void)in_sizes; (void)n_in; (void)out_size; (void)ws_size;

  char* ws = (char*)d_ws;
  size_t off = 0;
  auto alloc = [&](size_t bytes) -> void* {
    void* p = ws + off;
    off += (bytes + 255) & ~(size_t)255;
    return p;
  };

  u16* wqkv_t = (u16*)alloc((size_t)QKVLD * CCH * 2);         // (1152,384) frag-linear, g1-scaled
  u16* wp_t   = (u16*)alloc((size_t)CCH * CCH * 2);           // (384,384)  frag-linear
  u16* w1_t   = (u16*)alloc((size_t)4 * CCH * CCH * 2);       // (1536,384) frag-linear, g2-scaled
  u16* w2_t   = (u16*)alloc((size_t)CCH * 4 * CCH * 2);       // (384,1536) frag-linear
  u16*   xb   = (u16*)alloc((size_t)BTT * CCH * 2);           // bf16 cast of x
  u16*   h_b  = (u16*)alloc((size_t)BTT * CCH * 2);           // attn-out
  u16*   x2   = (u16*)alloc((size_t)BTT * CCH * 2);           // bf16 residual stream
  u16*   qkv_b = (u16*)alloc((size_t)BTT * 4 * CCH * 2);      // (BT,1152) then u (BT,1536)
  u16*   u_b   = qkv_b;
  float* st1  = (float*)alloc((size_t)BTT * 2 * 4);           // LN1 {mu, rinv}
  float* st2p = (float*)alloc((size_t)BTT * 4 * 4);           // LN2 partials {p0,q0,p1,q1}
  float* c1q  = (float*)alloc(1152 * 4);
  float* c2q  = (float*)alloc(1152 * 4);
  float* c1m  = (float*)alloc(1536 * 4);
  float* c2m  = (float*)alloc(1536 * 4);

  // repack + x-cast + LN1 stats + c1/c2, ONE launch
  prep_all<<<15776, 256, 0, stream>>>(wq, wk, wv, wproj, w1, w2,
                                      wqkv_t, wp_t, w1_t, w2_t,
                                      x, ln1g, ln1b, ln2g, ln2b,
                                      xb, st1, c1q, c2q, c1m, c2m);

  // fused QKV with LN1 fold: reads raw xb, applies {rinv,mu*c1,c2} in epilogue
  gemm_kres3<0, 0, 0, 1, 0, 1, 0><<<dim3(6, 512), 192, 0, stream>>>(
      xb, wqkv_t, nullptr, nullptr, qkv_b, BTT, QKVLD, st1, nullptr, c1q, c2q);

  // attention -> h_b
  attn_mfma<<<BB * NHH, 1024, 0, stream>>>(qkv_b, h_b);

  // x2 = x + attn @ wproj + bproj; emits LN2 partial row stats
  gemm_kres3<1, 1, 0, 1, 0, 0, 1><<<dim3(2, 512), 192, 0, stream>>>(
      h_b, wp_t, bproj, x, x2, BTT, CCH, nullptr, st2p, nullptr, nullptr);

  // u = relu(LN2(x2) @ w1 + b1) with LN2 fold from partials: reads x2 directly
  gemm_kres3<1, 0, 1, 1, 0, 2, 0><<<dim3(8, 512), 192, 0, stream>>>(
      x2, w1_t, b1, nullptr, u_b, BTT, 4 * CCH, st2p, nullptr, c1m, c2m);

  // out = x2 + u @ w2 + b2  (fp32 out, bf16 res) -- K=1536, R8 path
  gemm_mfma<1, 1, 0, 0, 1><<<dim3(3, 256), 256, 0, stream>>>(u_b, w2_t, b2, x2, out,
                                                             BTT, CCH, 4 * CCH);
}

// Round 16
// 331.002 us; speedup vs baseline: 1.1066x; 1.1066x over previous
//
#include <hip/hip_runtime.h>

#define BB 128
#define TT 256
#define CCH 384
#define NHH 6
#define HSZ 64
#define BTT (BB*TT)
#define QKVLD 1152

typedef unsigned short u16;
typedef unsigned int   u32;
typedef __attribute__((ext_vector_type(8))) short  short8;   // 8 x bf16 (4 VGPR)
typedef __attribute__((ext_vector_type(4))) float  floatx4;  // MFMA C/D

__device__ __forceinline__ u16 f2bf(float f) {
  union { float f; u32 i; } v; v.f = f; u32 x = v.i;
  return (u16)((x + 0x7fffu + ((x >> 16) & 1u)) >> 16);
}
__device__ __forceinline__ float bf2f(u16 w) {
  union { u32 i; float f; } v; v.i = ((u32)w) << 16; return v.f;
}

// async global->LDS, 16B per lane; LDS dest is wave-uniform base + lane*16
__device__ __forceinline__ void gll16(const u16* g, u16* l) {
  __builtin_amdgcn_global_load_lds((const __attribute__((address_space(1))) void*)g,
                                   (__attribute__((address_space(3))) void*)l, 16, 0, 0);
}

// ---------------- LayerNorm: bf16 in -> bf16 out, one wave per row, 4 rows/block ----
template <int INBF>
__global__ __launch_bounds__(256) void ln_kernel(const void* __restrict__ xv,
                                                 const float* __restrict__ g,
                                                 const float* __restrict__ b,
                                                 u16* __restrict__ out) {
  int row = blockIdx.x * 4 + (threadIdx.x >> 6);
  int lane = threadIdx.x & 63;
  float vals[6];
  float sum = 0.f;
  if (INBF) {
    const u16* xr = (const u16*)xv + (size_t)row * CCH;
#pragma unroll
    for (int i = 0; i < 6; ++i) { vals[i] = bf2f(xr[lane + (i << 6)]); sum += vals[i]; }
  } else {
    const float* xr = (const float*)xv + (size_t)row * CCH;
#pragma unroll
    for (int i = 0; i < 6; ++i) { vals[i] = xr[lane + (i << 6)]; sum += vals[i]; }
  }
#pragma unroll
  for (int off = 32; off; off >>= 1) sum += __shfl_xor(sum, off);
  float mean = sum * (1.f / 384.f);
  float vs = 0.f;
#pragma unroll
  for (int i = 0; i < 6; ++i) { float d = vals[i] - mean; vs += d * d; }
#pragma unroll
  for (int off = 32; off; off >>= 1) vs += __shfl_xor(vs, off);
  float rinv = rsqrtf(vs * (1.f / 384.f) + 1e-5f);
  u16* orow = out + (size_t)row * CCH;
#pragma unroll
  for (int i = 0; i < 6; ++i) {
    int c = lane + (i << 6);
    orow[c] = f2bf((vals[i] - mean) * rinv * g[c] + b[c]);
  }
}

// ------------- prep_all: weight repack (frag-linear) + LN1, ONE launch (R14-proven) ----
// Blocks [0,6912): repack.  Blocks [6912,15104): LN1 over x (fp32 in).
// Bp[((nb*KT + kt)*64 + lane)*8 + e] = W[nb*16 + (lane&15)][kt*32 + (lane>>4)*8 + e]
__global__ __launch_bounds__(256) void prep_all(const float* __restrict__ wq,
                                                const float* __restrict__ wk,
                                                const float* __restrict__ wv,
                                                const float* __restrict__ wproj,
                                                const float* __restrict__ w1,
                                                const float* __restrict__ w2,
                                                u16* __restrict__ wqkv_t, u16* __restrict__ wp_t,
                                                u16* __restrict__ w1_t, u16* __restrict__ w2_t,
                                                const float* __restrict__ x,
                                                const float* __restrict__ ln1g,
                                                const float* __restrict__ ln1b,
                                                u16* __restrict__ h_out) {
  const int bidx = blockIdx.x;
  if (bidx < 6912) {
    int idx = bidx * 256 + threadIdx.x;
    const int S1 = 442368;            // 72 nb * 12 kt * 512
    const int S2 = S1 + 147456;       // 24 * 12 * 512
    const int S3 = S2 + 589824;       // 96 * 12 * 512
    const int S4 = S3 + 589824;       // 24 * 48 * 512
    if (idx < S1) {
      int i = idx, e = i & 7, l = (i >> 3) & 63, r = i >> 9;
      int kt = r % 12, nb = r / 12;
      int n = nb * 16 + (l & 15), k = kt * 32 + (l >> 4) * 8 + e;
      int sel = n / 384, nn = n % 384;
      size_t src = ((size_t)(nn >> 6) * 384 + k) * 64 + (nn & 63);
      float v = (sel == 0) ? wq[src] : (sel == 1) ? wk[src] : wv[src];
      wqkv_t[i] = f2bf(v);
    } else if (idx < S2) {
      int i = idx - S1, e = i & 7, l = (i >> 3) & 63, r = i >> 9;
      int kt = r % 12, nb = r / 12;
      int n = nb * 16 + (l & 15), k = kt * 32 + (l >> 4) * 8 + e;
      wp_t[i] = f2bf(wproj[(size_t)k * 384 + n]);
    } else if (idx < S3) {
      int i = idx - S2, e = i & 7, l = (i >> 3) & 63, r = i >> 9;
      int kt = r % 12, nb = r / 12;
      int n = nb * 16 + (l & 15), k = kt * 32 + (l >> 4) * 8 + e;
      w1_t[i] = f2bf(w1[(size_t)k * 1536 + n]);
    } else if (idx < S4) {
      int i = idx - S3, e = i & 7, l = (i >> 3) & 63, r = i >> 9;
      int kt = r % 48, nb = r / 48;
      int n = nb * 16 + (l & 15), k = kt * 32 + (l >> 4) * 8 + e;
      w2_t[i] = f2bf(w2[(size_t)k * 384 + n]);
    }
  } else {
    int row = (bidx - 6912) * 4 + (threadIdx.x >> 6);
    int lane = threadIdx.x & 63;
    const float* xr = x + (size_t)row * CCH;
    float vals[6];
    float sum = 0.f;
#pragma unroll
    for (int i = 0; i < 6; ++i) { vals[i] = xr[lane + (i << 6)]; sum += vals[i]; }
#pragma unroll
    for (int off = 32; off; off >>= 1) sum += __shfl_xor(sum, off);
    float mean = sum * (1.f / 384.f);
    float vs = 0.f;
#pragma unroll
    for (int i = 0; i < 6; ++i) { float d = vals[i] - mean; vs += d * d; }
#pragma unroll
    for (int off = 32; off; off >>= 1) vs += __shfl_xor(vs, off);
    float rinv = rsqrtf(vs * (1.f / 384.f) + 1e-5f);
    u16* orow = h_out + (size_t)row * CCH;
#pragma unroll
    for (int i = 0; i < 6; ++i) {
      int c = lane + (i << 6);
      orow[c] = f2bf((vals[i] - mean) * rinv * ln1g[c] + ln1b[c]);
    }
  }
}

// ---- gemm_kres3: K=384-resident GEMM, 64x192 block, 3 waves 1Mx3N ----
// R13-proven best config: per-kt [64][32] chunk-XOR A-tiles (0 conflicts),
// disjoint per-wave B reg-prefetch DEPTH-2 (measured: d1=58.8, d2=54.4,
// d3=55.3 us on MLP1 -- depth-2 is the optimum), one stage-barrier then
// barrier-free fully-unrolled k-loop. VGPR 84, ~19.5% occupancy.
template <int BIAS, int RES, int RELU, int OUTBF, int RESBF>
__global__ __launch_bounds__(192, 2) void gemm_kres3(const u16* __restrict__ A,
                                                     const u16* __restrict__ Bp,
                                                     const float* __restrict__ bias,
                                                     const void* __restrict__ resv,
                                                     void* __restrict__ outv,
                                                     int M, int N) {
  __shared__ __align__(16) u16 Ah[12 * 2048];   // 12 kt-tiles of [64][32], 48 KB
  const int tid = threadIdx.x;
  const int lane = tid & 63;
  const int w = tid >> 6;                 // wave 0..2; owns cols [64w, 64w+64)

  // XCD swizzle (bijective since nwg % 8 == 0)
  const int gx = gridDim.x;
  const int nwg = gx * gridDim.y;
  const int bid = blockIdx.y * gx + blockIdx.x;
  const int lin = (bid & 7) * (nwg >> 3) + (bid >> 3);
  const int m0 = (lin / gx) * 64, n0 = (lin % gx) * 192;

  const int lm = lane & 15, qd = lane >> 4;

  // ---- stage all 12 A kt-tiles: 16 gll16/wave, chunk-XOR per tile ----
#pragma unroll
  for (int g = 0; g < 16; ++g) {
    int call = w * 16 + g;                // 0..47
    int kt = call >> 2, c = call & 3;     // tile, 16-row group
    int row = 16 * c + (lane >> 2);
    int ch = (lane & 3) ^ ((row >> 1) & 3);
    const u16* src = A + (size_t)(m0 + row) * 384 + kt * 32 + ch * 8;
    gll16(src, &Ah[kt * 2048 + c * 512]);
  }

  // B fragment bases: wave w's 4 n-blocks (nb = n0/16 + 4w + j), KT=12
  const u16* bsrc[4];
#pragma unroll
  for (int j = 0; j < 4; ++j)
    bsrc[j] = Bp + ((size_t)((n0 >> 4) + 4 * w + j) * 12) * 512 + lane * 8;

  floatx4 acc[4][4];
  floatx4 zero4 = {0.f, 0.f, 0.f, 0.f};
#pragma unroll
  for (int i = 0; i < 4; ++i)
#pragma unroll
    for (int j = 0; j < 4; ++j) acc[i][j] = zero4;

  // depth-2 B prefetch: 3-buffer rotation (all indices static after unroll)
  short8 bf[3][4];
#pragma unroll
  for (int j = 0; j < 4; ++j) bf[0][j] = *(const short8*)(bsrc[j]);          // kt=0
#pragma unroll
  for (int j = 0; j < 4; ++j) bf[1][j] = *(const short8*)(bsrc[j] + 512);    // kt=1

  asm volatile("s_waitcnt vmcnt(0)" ::: "memory");   // A-tiles + bf[0..1] resident
  __syncthreads();                                   // the ONLY barrier

  // ---- barrier-free k-loop, fully unrolled, depth-2 B pipeline ----
#pragma unroll
  for (int kt = 0; kt < 12; ++kt) {
    if (kt + 2 < 12) {
      const int pb = (kt + 2) % 3;
#pragma unroll
      for (int j = 0; j < 4; ++j)
        bf[pb][j] = *(const short8*)(bsrc[j] + (kt + 2) * 512);
    }
    const int cb = kt % 3;
    short8 af[4];
#pragma unroll
    for (int i = 0; i < 4; ++i) {
      int rm = 16 * i + lm;
      af[i] = *(const short8*)&Ah[kt * 2048 + rm * 32 + (qd ^ ((rm >> 1) & 3)) * 8];
    }
#pragma unroll
    for (int i = 0; i < 4; ++i)
#pragma unroll
      for (int j = 0; j < 4; ++j)
        acc[i][j] = __builtin_amdgcn_mfma_f32_16x16x32_bf16(af[i], bf[cb][j], acc[i][j], 0, 0, 0);
  }

  // epilogue: C/D layout col=lm, row=qd*4+r
#pragma unroll
  for (int i = 0; i < 4; ++i) {
    int row0 = m0 + 16 * i + qd * 4;
#pragma unroll
    for (int j = 0; j < 4; ++j) {
      int col = n0 + 64 * w + 16 * j + lm;
      float bb = 0.f;
      if (BIAS) bb = bias[col];
#pragma unroll
      for (int r = 0; r < 4; ++r) {
        size_t idx = (size_t)(row0 + r) * N + col;
        float val = acc[i][j][r] + bb;
        if (RES) val += RESBF ? bf2f(((const u16*)resv)[idx]) : ((const float*)resv)[idx];
        if (RELU) val = fmaxf(val, 0.f);
        if (OUTBF) ((u16*)outv)[idx] = f2bf(val);
        else       ((float*)outv)[idx] = val;
      }
    }
  }
}

// ---- MFMA GEMM v3 (R8-proven, for MLP2 K=1536): 128x128 tile, BK=32,
// A in LDS dbuf, B register-direct from frag-linear Bp, depth-1 prefetch. ----
template <int BIAS, int RES, int RELU, int OUTBF, int RESBF>
__global__ __launch_bounds__(256, 3) void gemm_mfma(const u16* __restrict__ A,
                                                    const u16* __restrict__ Bp,
                                                    const float* __restrict__ bias,
                                                    const void* __restrict__ resv,
                                                    void* __restrict__ outv,
                                                    int M, int N, int K) {
  __shared__ __align__(16) u16 As[2][128 * 32];
  const int tid = threadIdx.x;
  const int lane = tid & 63;
  const int w = tid >> 6;                 // wave 0..3
  const int wr = w >> 1, wc = w & 1;      // 2x2 wave grid, wave tile 64x64

  const int gx = gridDim.x;
  const int nwg = gx * gridDim.y;
  const int bid = blockIdx.y * gx + blockIdx.x;
  const int lin = (bid & 7) * (nwg >> 3) + (bid >> 3);
  const int m0 = (lin / gx) * 128, n0 = (lin % gx) * 128;

  const int lm = lane & 15, qd = lane >> 4;
  const int KT = K >> 5;

  floatx4 acc[4][4];
  floatx4 zero4 = {0.f, 0.f, 0.f, 0.f};
#pragma unroll
  for (int i = 0; i < 4; ++i)
#pragma unroll
    for (int j = 0; j < 4; ++j) acc[i][j] = zero4;

  const u16* srcA[2];
#pragma unroll
  for (int c = 0; c < 2; ++c) {
    int row = 32 * w + 16 * c + (lane >> 2);
    int ch = (lane & 3) ^ ((row >> 1) & 3);
    srcA[c] = A + (size_t)(m0 + row) * K + ch * 8;
  }
  const int dA = (32 * w) * 32;

  const u16* bsrc[4];
#pragma unroll
  for (int j = 0; j < 4; ++j)
    bsrc[j] = Bp + ((size_t)((n0 >> 4) + 4 * wc + j) * KT) * 512 + lane * 8;

#pragma unroll
  for (int c = 0; c < 2; ++c) gll16(srcA[c], &As[0][dA + 512 * c]);
  short8 bcur[4], bnxt[4];
#pragma unroll
  for (int j = 0; j < 4; ++j) bcur[j] = *(const short8*)(bsrc[j]);

  for (int k0 = 0; k0 < K; k0 += 64) {
    __syncthreads();
    {
      int kn = k0 + 32;
      int kto = (kn >> 5) << 9;
#pragma unroll
      for (int j = 0; j < 4; ++j) bnxt[j] = *(const short8*)(bsrc[j] + kto);
#pragma unroll
      for (int c = 0; c < 2; ++c) gll16(srcA[c] + kn, &As[1][dA + 512 * c]);
      short8 af[4];
#pragma unroll
      for (int i = 0; i < 4; ++i) {
        int rm = 64 * wr + 16 * i + lm;
        af[i] = *(const short8*)&As[0][rm * 32 + (qd ^ ((rm >> 1) & 3)) * 8];
      }
#pragma unroll
      for (int i = 0; i < 4; ++i)
#pragma unroll
        for (int j = 0; j < 4; ++j)
          acc[i][j] = __builtin_amdgcn_mfma_f32_16x16x32_bf16(af[i], bcur[j], acc[i][j], 0, 0, 0);
    }
    __syncthreads();
    {
      int kn = k0 + 64;
      if (kn < K) {
        int kto = (kn >> 5) << 9;
#pragma unroll
        for (int j = 0; j < 4; ++j) bcur[j] = *(const short8*)(bsrc[j] + kto);
#pragma unroll
        for (int c = 0; c < 2; ++c) gll16(srcA[c] + kn, &As[0][dA + 512 * c]);
      }
      short8 af[4];
#pragma unroll
      for (int i = 0; i < 4; ++i) {
        int rm = 64 * wr + 16 * i + lm;
        af[i] = *(const short8*)&As[1][rm * 32 + (qd ^ ((rm >> 1) & 3)) * 8];
      }
#pragma unroll
      for (int i = 0; i < 4; ++i)
#pragma unroll
        for (int j = 0; j < 4; ++j)
          acc[i][j] = __builtin_amdgcn_mfma_f32_16x16x32_bf16(af[i], bnxt[j], acc[i][j], 0, 0, 0);
    }
  }

#pragma unroll
  for (int i = 0; i < 4; ++i) {
    int row0 = m0 + 64 * wr + 16 * i + qd * 4;
#pragma unroll
    for (int j = 0; j < 4; ++j) {
      int col = n0 + 64 * wc + 16 * j + lm;
      float bb = 0.f;
      if (BIAS) bb = bias[col];
#pragma unroll
      for (int r = 0; r < 4; ++r) {
        size_t idx = (size_t)(row0 + r) * N + col;
        float val = acc[i][j][r] + bb;
        if (RES) val += RESBF ? bf2f(((const u16*)resv)[idx]) : ((const float*)resv)[idx];
        if (RELU) val = fmaxf(val, 0.f);
        if (OUTBF) ((u16*)outv)[idx] = f2bf(val);
        else       ((float*)outv)[idx] = val;
      }
    }
  }
}

// ---------------- MFMA attention, column(query-axis) softmax ----------------
#define ASCALE 0.051031036307982884f

__global__ __launch_bounds__(1024) void attn_mfma(const u16* __restrict__ qkv,
                                                  u16* __restrict__ out) {
  __shared__ __align__(16) char lds_raw[36864 + 20480 + 2048];
  u16*   Ks       = (u16*)lds_raw;
  u16*   VT       = (u16*)lds_raw;
  float* partials = (float*)(lds_raw + 36864);
  u16*   stage    = (u16*)(lds_raw + 36864);
  float* gmax     = (float*)(lds_raw + 57344);
  float* linv     = (float*)(lds_raw + 58368);

  const int tid = threadIdx.x;
  const int lane = tid & 63;
  const int w = tid >> 6;           // wave 0..15 owns S rows [16w,16w+16)
  const int lm = lane & 15, qd = lane >> 4;
  const int b = blockIdx.x / NHH, h = blockIdx.x % NHH;
  const size_t rowbase = (size_t)b * TT;
  const u16* qp = qkv + rowbase * QKVLD + h * HSZ;
  const u16* kp = qp + 384;
  const u16* vp = qp + 768;

  {
    int s = tid >> 2, c4 = tid & 3;
    const u16* src = kp + (size_t)s * QKVLD;
    *(uint4*)&Ks[s * 72 + c4 * 8]       = *(const uint4*)(src + c4 * 8);
    *(uint4*)&Ks[s * 72 + (c4 + 4) * 8] = *(const uint4*)(src + (c4 + 4) * 8);
  }
  short8 qf0, qf1;
  {
    const u16* qrow = qp + (size_t)(16 * w + lm) * QKVLD + qd * 8;
    qf0 = *(const short8*)(qrow);
    qf1 = *(const short8*)(qrow + 32);
  }
  __syncthreads();

  floatx4 acc[16];
  floatx4 zero4 = {0.f, 0.f, 0.f, 0.f};
#pragma unroll
  for (int tc = 0; tc < 16; ++tc) acc[tc] = zero4;

#pragma unroll
  for (int tc = 0; tc < 16; ++tc) {
    if (tc <= w) {
      int sr = 16 * tc + lm;
      short8 kf0 = *(const short8*)&Ks[sr * 72 + qd * 8];
      short8 kf1 = *(const short8*)&Ks[sr * 72 + 32 + qd * 8];
      acc[tc] = __builtin_amdgcn_mfma_f32_16x16x32_bf16(qf0, kf0, acc[tc], 0, 0, 0);
      acc[tc] = __builtin_amdgcn_mfma_f32_16x16x32_bf16(qf1, kf1, acc[tc], 0, 0, 0);
    }
  }

  const int rb = 16 * w + qd * 4;
  float pmax[16];
#pragma unroll
  for (int tc = 0; tc < 16; ++tc) {
    float m = -1e30f;
    if (tc <= w) {
      int sc = 16 * tc + lm;
#pragma unroll
      for (int r = 0; r < 4; ++r) {
        float vv = acc[tc][r] * ASCALE;
        vv = (rb + r >= sc) ? vv : -1e30f;
        acc[tc][r] = vv;
        m = fmaxf(m, vv);
      }
    }
    m = fmaxf(m, __shfl_xor(m, 16));
    m = fmaxf(m, __shfl_xor(m, 32));
    pmax[tc] = m;
  }
  if (lane < 16) {
#pragma unroll
    for (int tc = 0; tc < 16; ++tc) partials[w * 256 + tc * 16 + lane] = pmax[tc];
  }
  __syncthreads();
  if (tid < 256) {
    float m = partials[tid];
#pragma unroll
    for (int i = 1; i < 16; ++i) m = fmaxf(m, partials[i * 256 + tid]);
    gmax[tid] = m;
  }
  __syncthreads();

  float psum[16];
#pragma unroll
  for (int tc = 0; tc < 16; ++tc) {
    float s = 0.f;
    if (tc <= w) {
      float gm = gmax[tc * 16 + lm];
#pragma unroll
      for (int r = 0; r < 4; ++r) {
        float e = (acc[tc][r] > -1e29f) ? __expf(acc[tc][r] - gm) : 0.f;
        acc[tc][r] = e;
        s += e;
      }
    }
    s += __shfl_xor(s, 16);
    s += __shfl_xor(s, 32);
    psum[tc] = s;
  }
  if (lane < 16) {
#pragma unroll
    for (int tc = 0; tc < 16; ++tc) partials[w * 256 + tc * 16 + lane] = psum[tc];
  }
  __syncthreads();
  if (tid < 256) {
    float s = partials[tid];
#pragma unroll
    for (int i = 1; i < 16; ++i) s += partials[i * 256 + tid];
    linv[tid] = 1.f / s;
  }
  __syncthreads();

  {
    int s = tid >> 2, dg = (tid & 3) * 16;
    const u16* vrow = vp + (size_t)s * QKVLD + dg;
    u16 tmp[16];
    *(uint4*)&tmp[0] = *(const uint4*)(vrow);
    *(uint4*)&tmp[8] = *(const uint4*)(vrow + 8);
#pragma unroll
    for (int j = 0; j < 16; ++j) VT[(dg + j) * 264 + s] = tmp[j];
  }
  __syncthreads();

  u16* mst = stage + w * 640;
  floatx4 oacc[4];
#pragma unroll
  for (int nt = 0; nt < 4; ++nt) oacc[nt] = zero4;

#pragma unroll
  for (int c = 0; c < 8; ++c) {
    if (2 * c <= w) {
#pragma unroll
      for (int tt = 0; tt < 2; ++tt) {
        int tc = 2 * c + tt;
        float li = (tc <= w) ? linv[tc * 16 + lm] : 0.f;
#pragma unroll
        for (int r = 0; r < 4; ++r) {
          float pv = (tc <= w) ? acc[tc][r] * li : 0.f;
          mst[(qd * 4 + r) * 40 + tt * 16 + lm] = f2bf(pv);
        }
      }
      asm volatile("s_waitcnt lgkmcnt(0)" ::: "memory");
      short8 pf = *(const short8*)&mst[lm * 40 + qd * 8];
#pragma unroll
      for (int nt = 0; nt < 4; ++nt) {
        short8 vf = *(const short8*)&VT[(nt * 16 + lm) * 264 + c * 32 + qd * 8];
        oacc[nt] = __builtin_amdgcn_mfma_f32_16x16x32_bf16(pf, vf, oacc[nt], 0, 0, 0);
      }
      asm volatile("" ::: "memory");
    }
  }

  u16* ob = out + rowbase * CCH + h * HSZ;
#pragma unroll
  for (int nt = 0; nt < 4; ++nt) {
#pragma unroll
    for (int r = 0; r < 4; ++r) {
      int t = 16 * w + qd * 4 + r;
      ob[(size_t)t * CCH + nt * 16 + lm] = f2bf(oacc[nt][r]);
    }
  }
}

// ---------------- launch ----------------
extern "C" void kernel_launch(void* const* d_in, const int* in_sizes, int n_in,
                              void* d_out, int out_size, void* d_ws, size_t ws_size,
                              hipStream_t stream) {
  const float* x     = (const float*)d_in[0];
  const float* wq    = (const float*)d_in[1];
  const float* wk    = (const float*)d_in[2];
  const float* wv    = (const float*)d_in[3];
  const float* wproj = (const float*)d_in[4];
  const float* bproj = (const float*)d_in[5];
  const float* w1    = (const float*)d_in[6];
  const float* b1    = (const float*)d_in[7];
  const float* w2    = (const float*)d_in[8];
  const float* b2    = (const float*)d_in[9];
  const float* ln1g  = (const float*)d_in[10];
  const float* ln1b  = (const float*)d_in[11];
  const float* ln2g  = (const float*)d_in[12];
  const float* ln2b  = (const float*)d_in[13];
  float* out = (float*)d_out;
  (void)in_sizes; (void)n_in; (void)out_size; (void)ws_size;

  char* ws = (char*)d_ws;
  size_t off = 0;
  auto alloc = [&](size_t bytes) -> void* {
    void* p = ws + off;
    off += (bytes + 255) & ~(size_t)255;
    return p;
  };

  u16* wqkv_t = (u16*)alloc((size_t)QKVLD * CCH * 2);         // (1152,384) frag-linear
  u16* wp_t   = (u16*)alloc((size_t)CCH * CCH * 2);           // (384,384)  frag-linear
  u16* w1_t   = (u16*)alloc((size_t)4 * CCH * CCH * 2);       // (1536,384) frag-linear
  u16* w2_t   = (u16*)alloc((size_t)CCH * 4 * CCH * 2);       // (384,1536) frag-linear
  u16*   h_b  = (u16*)alloc((size_t)BTT * CCH * 2);           // LN1 / attn-out / LN2
  u16*   x2   = (u16*)alloc((size_t)BTT * CCH * 2);           // bf16 residual stream
  u16*   qkv_b = (u16*)alloc((size_t)BTT * 4 * CCH * 2);      // (BT,1152) then u (BT,1536)
  u16*   u_b   = qkv_b;

  // repack + LN1 in ONE launch (blocks [0,6912) repack, [6912,15104) LN1)
  prep_all<<<15104, 256, 0, stream>>>(wq, wk, wv, wproj, w1, w2,
                                      wqkv_t, wp_t, w1_t, w2_t,
                                      x, ln1g, ln1b, h_b);

  // fused QKV: (BT,1152), K=384 resident, barrier-free, B disjoint, depth-2
  gemm_kres3<0, 0, 0, 1, 0><<<dim3(6, 512), 192, 0, stream>>>(h_b, wqkv_t, nullptr, nullptr,
                                                              qkv_b, BTT, QKVLD);
  // attention -> h_b (h dead)
  attn_mfma<<<BB * NHH, 1024, 0, stream>>>(qkv_b, h_b);

  // x2 = x + attn @ wproj + bproj  (bf16 out)
  gemm_kres3<1, 1, 0, 1, 0><<<dim3(2, 512), 192, 0, stream>>>(h_b, wp_t, bproj, x, x2,
                                                              BTT, CCH);
  // LN2 -> h_b (attn dead)
  ln_kernel<1><<<BTT / 4, 256, 0, stream>>>(x2, ln2g, ln2b, h_b);

  // u = relu(h2 @ w1 + b1): (BT,1536), K=384 resident, depth-2
  gemm_kres3<1, 0, 1, 1, 0><<<dim3(8, 512), 192, 0, stream>>>(h_b, w1_t, b1, nullptr, u_b,
                                                              BTT, 4 * CCH);
  // out = x2 + u @ w2 + b2  (fp32 out, bf16 res) -- K=1536, R8 path
  gemm_mfma<1, 1, 0, 0, 1><<<dim3(3, 256), 256, 0, stream>>>(u_b, w2_t, b2, x2, out,
                                                             BTT, CCH, 4 * CCH);
}